// Round 3
// baseline (2794.973 us; speedup 1.0000x reference)
//
#include <hip/hip_runtime.h>

#define NTOK  16384
#define INF   2048
#define OUTF  2048
#define RANK  45
#define GTOK  8
#define ACH   64
#define AROWS 64

// ---------------- Kernel A: t = x @ shared_in  [16384,2048]@[2048,45] ----------------
// 256 blocks x 512 thr. Block = 64 rows x 48 cols (45 + pad). K-chunks of 64 staged in
// LDS (x transposed for conflict-free reads), register-prefetch of next chunk (T14).
__global__ __launch_bounds__(512) void t_gemm2(
    const float* __restrict__ x, const float* __restrict__ si, float* __restrict__ t)
{
    __shared__ float x_t[ACH][AROWS + 2];   // [k][row], pad 2 -> 2-way max on reads
    __shared__ float si_l[ACH][48];         // [k][col], cols 45..47 zeroed
    const int tid  = threadIdx.x;
    const int rg   = tid & 31, cg = tid >> 5;
    const int row0 = rg * 2, c0 = cg * 3;   // 32x16 thread grid, 2x3 micro-tile
    const float4* __restrict__ xg = (const float4*)(x + (size_t)blockIdx.x * AROWS * INF);

    if (tid < ACH * 3) si_l[tid / 3][RANK + tid % 3] = 0.f;   // persistent zero pad

    float a00=0.f,a01=0.f,a02=0.f,a10=0.f,a11=0.f,a12=0.f;
    float4 px[2];
    float  ps[6];

    // prologue: chunk 0 into regs
#pragma unroll
    for (int s = 0; s < 2; ++s) {
        const int i4 = tid + s * 512;
        px[s] = xg[(i4 >> 4) * (INF / 4) + (i4 & 15)];
    }
#pragma unroll
    for (int s = 0; s < 6; ++s) {
        const int i = tid + s * 512;
        ps[s] = (i < ACH * RANK) ? si[i] : 0.f;     // (k0=0): si[k0*45 + i]
    }

    for (int ch = 0; ch < INF / ACH; ++ch) {
        // ---- write staged regs -> LDS
#pragma unroll
        for (int s = 0; s < 2; ++s) {
            const int i4 = tid + s * 512;
            const int r = i4 >> 4, kq = (i4 & 15) * 4;
            x_t[kq    ][r] = px[s].x;
            x_t[kq + 1][r] = px[s].y;
            x_t[kq + 2][r] = px[s].z;
            x_t[kq + 3][r] = px[s].w;
        }
#pragma unroll
        for (int s = 0; s < 6; ++s) {
            const int i = tid + s * 512;
            if (i < ACH * RANK) si_l[i / RANK][i % RANK] = ps[s];
        }
        __syncthreads();
        // ---- prefetch chunk ch+1 (overlaps with compute below)
        if (ch + 1 < INF / ACH) {
            const int k0 = (ch + 1) * ACH;
#pragma unroll
            for (int s = 0; s < 2; ++s) {
                const int i4 = tid + s * 512;
                px[s] = xg[(i4 >> 4) * (INF / 4) + (k0 >> 2) + (i4 & 15)];
            }
#pragma unroll
            for (int s = 0; s < 6; ++s) {
                const int i = tid + s * 512;
                ps[s] = (i < ACH * RANK) ? si[(size_t)k0 * RANK + i] : 0.f;
            }
        }
        // ---- compute 64 k-steps from LDS
#pragma unroll 4
        for (int k = 0; k < ACH; ++k) {
            const float2 xv = *(const float2*)&x_t[k][row0];
            const float s0 = si_l[k][c0], s1 = si_l[k][c0 + 1], s2 = si_l[k][c0 + 2];
            a00 += xv.x * s0; a01 += xv.x * s1; a02 += xv.x * s2;
            a10 += xv.y * s0; a11 += xv.y * s1; a12 += xv.y * s2;
        }
        __syncthreads();   // compute done -> LDS free for next chunk's writes
    }

    if (c0 < RANK) {
        float* __restrict__ t0 = t + ((size_t)blockIdx.x * AROWS + row0) * RANK + c0;
        t0[0] = a00; t0[1] = a01; t0[2] = a02;
        t0[RANK] = a10; t0[RANK + 1] = a11; t0[RANK + 2] = a12;
    }
}

// ---------------- Kernel B: out = t@so + gain * vec(V x U^T) ----------------
// block = GTOK tokens, 256 thr. Register-prefetch of token g+1's x/U/V (T14).
__global__ __launch_bounds__(256) void fused2(
    const float* __restrict__ x, const int* __restrict__ rid_p,
    const float* __restrict__ so, const float* __restrict__ rU,
    const float* __restrict__ rV, const float* __restrict__ gains,
    const float* __restrict__ t, float* __restrict__ out)
{
    __shared__ __align__(16) float x_lds[INF];        // 8 KB
    __shared__ __align__(16) float xu_t[32][68];      // [c][b]
    __shared__ __align__(16) float U_t[32][33];       // [a][c]
    __shared__ __align__(16) float V_lds[64][68];     // [d][b]
    __shared__ float t_lds[GTOK][RANK + 1];

    const int tid  = threadIdx.x;
    const int n0   = blockIdx.x * GTOK;
    const int c0   = tid & 15;
    const int dgrp = tid >> 4;
    const int cx   = tid & 31;
    const int bg   = tid >> 5;

    // token metadata up-front (latency hidden under base loop)
    const int4 r4a = ((const int4*)(rid_p + n0))[0];
    const int4 r4b = ((const int4*)(rid_p + n0))[1];
    const int rids[GTOK] = {r4a.x, r4a.y, r4a.z, r4a.w, r4b.x, r4b.y, r4b.z, r4b.w};
    float gg[GTOK];
#pragma unroll
    for (int g = 0; g < GTOK; ++g) gg[g] = gains[rids[g]];

    // prefetch token 0 staging into regs
    float4 pxr[2][2], pu[2], pv[2][4];
    {
        const float4* __restrict__ xg = (const float4*)(x + (size_t)n0 * INF);
        const float4* __restrict__ Ug = (const float4*)(rU + (size_t)rids[0] * 1024);
        const float4* __restrict__ Vg = (const float4*)(rV + (size_t)rids[0] * 4096);
        pxr[0][0] = xg[tid]; pxr[0][1] = xg[tid + 256];
        pu[0] = Ug[tid];
#pragma unroll
        for (int i = 0; i < 4; ++i) pv[0][i] = Vg[tid + i * 256];
    }

    for (int i = tid; i < GTOK * RANK; i += 256) {
        const int g = i / RANK, r = i - g * RANK;
        t_lds[g][r] = t[(size_t)(n0 + g) * RANK + r];
    }

    float acc[GTOK][8];
#pragma unroll
    for (int g = 0; g < GTOK; ++g)
#pragma unroll
        for (int j = 0; j < 8; ++j) acc[g][j] = 0.f;

    __syncthreads();

    // ---- base: acc[g][j] += sum_k t[g][k] * so[k][col_j]
#pragma unroll 3
    for (int k = 0; k < RANK; ++k) {
        float sv[8];
#pragma unroll
        for (int jd = 0; jd < 4; ++jd)
#pragma unroll
            for (int jc = 0; jc < 2; ++jc)
                sv[jd * 2 + jc] = so[(size_t)k * OUTF + (dgrp + 16 * jd) * 32 + c0 + 16 * jc];
#pragma unroll
        for (int g = 0; g < GTOK; ++g) {
            const float tv = t_lds[g][k];
#pragma unroll
            for (int j = 0; j < 8; ++j) acc[g][j] += tv * sv[j];
        }
    }

    // ---- adapter: fully unrolled token loop, double-buffered reg prefetch
#pragma unroll
    for (int g = 0; g < GTOK; ++g) {
        const int pb = g & 1;
        __syncthreads();   // previous token's LDS readers done
        ((float4*)x_lds)[tid]       = pxr[pb][0];
        ((float4*)x_lds)[tid + 256] = pxr[pb][1];
        {
            const int a0 = (4 * tid) & 31, cc = tid >> 3;
            U_t[a0    ][cc] = pu[pb].x;
            U_t[a0 + 1][cc] = pu[pb].y;
            U_t[a0 + 2][cc] = pu[pb].z;
            U_t[a0 + 3][cc] = pu[pb].w;
        }
#pragma unroll
        for (int i = 0; i < 4; ++i) {
            const int i4 = tid + i * 256;
            *(float4*)&V_lds[i4 >> 4][(i4 & 15) * 4] = pv[pb][i];
        }
        // issue next token's loads (latency hides under xu+vxu)
        if (g + 1 < GTOK) {
            const int nb = pb ^ 1;
            const float4* __restrict__ xg = (const float4*)(x + (size_t)(n0 + g + 1) * INF);
            const float4* __restrict__ Ug = (const float4*)(rU + (size_t)rids[g + 1] * 1024);
            const float4* __restrict__ Vg = (const float4*)(rV + (size_t)rids[g + 1] * 4096);
            pxr[nb][0] = xg[tid]; pxr[nb][1] = xg[tid + 256];
            pu[nb] = Ug[tid];
#pragma unroll
            for (int i = 0; i < 4; ++i) pv[nb][i] = Vg[tid + i * 256];
        }
        __syncthreads();

        // xu[b][cx] = sum_a x[b*32+a] * U[cx][a],  b = bg*8 + jj
        float xacc[8];
#pragma unroll
        for (int jj = 0; jj < 8; ++jj) xacc[jj] = 0.f;
        for (int a = 0; a < 32; a += 4) {
            const float u0 = U_t[a][cx], u1 = U_t[a + 1][cx];
            const float u2 = U_t[a + 2][cx], u3 = U_t[a + 3][cx];
#pragma unroll
            for (int jj = 0; jj < 8; ++jj) {
                const float4 xv = *(const float4*)&x_lds[(bg * 8 + jj) * 32 + a];
                xacc[jj] += xv.x * u0 + xv.y * u1 + xv.z * u2 + xv.w * u3;
            }
        }
#pragma unroll
        for (int jj = 0; jj < 8; ++jj) xu_t[cx][bg * 8 + jj] = xacc[jj];
        __syncthreads();

        // vxu[d][c] = sum_b V[d][b] * xu[b][c]
        float vtmp[8];
#pragma unroll
        for (int j = 0; j < 8; ++j) vtmp[j] = 0.f;
        for (int b = 0; b < 64; b += 4) {
            const float4 xc0 = *(const float4*)&xu_t[c0][b];
            const float4 xc1 = *(const float4*)&xu_t[c0 + 16][b];
#pragma unroll
            for (int jd = 0; jd < 4; ++jd) {
                const float4 vv = *(const float4*)&V_lds[dgrp + 16 * jd][b];
                vtmp[jd * 2]     += vv.x * xc0.x + vv.y * xc0.y + vv.z * xc0.z + vv.w * xc0.w;
                vtmp[jd * 2 + 1] += vv.x * xc1.x + vv.y * xc1.y + vv.z * xc1.z + vv.w * xc1.w;
            }
        }
#pragma unroll
        for (int j = 0; j < 8; ++j) acc[g][j] += gg[g] * vtmp[j];
    }

    // ---- store
#pragma unroll
    for (int g = 0; g < GTOK; ++g) {
        float* __restrict__ orow = out + (size_t)(n0 + g) * OUTF;
#pragma unroll
        for (int jd = 0; jd < 4; ++jd)
#pragma unroll
            for (int jc = 0; jc < 2; ++jc)
                orow[(dgrp + 16 * jd) * 32 + c0 + 16 * jc] = acc[g][jd * 2 + jc];
    }
}

extern "C" void kernel_launch(void* const* d_in, const int* in_sizes, int n_in,
                              void* d_out, int out_size, void* d_ws, size_t ws_size,
                              hipStream_t stream) {
    const float* x   = (const float*)d_in[0];
    const int*   rid = (const int*)d_in[1];
    const float* si  = (const float*)d_in[2];
    const float* so  = (const float*)d_in[3];
    const float* rU  = (const float*)d_in[4];
    const float* rV  = (const float*)d_in[5];
    const float* rg  = (const float*)d_in[6];
    float* out = (float*)d_out;
    float* t   = (float*)d_ws;                    // N*45*4 = 2.95 MB scratch

    t_gemm2<<<NTOK / AROWS, 512, 0, stream>>>(x, si, t);
    fused2<<<NTOK / GTOK, 256, 0, stream>>>(x, rid, so, rU, rV, rg, t, out);
}